// Round 2
// baseline (3077.219 us; speedup 1.0000x reference)
//
#include <hip/hip_runtime.h>
#include <hip/hip_bf16.h>
#include <math.h>

// ---------------------------------------------------------------------------
// LSTM_55327768708454:  T=128 B=256 D=512 H=1024 O=1
//   x  = relu(inputs @ W1^T + b1)                    (T,B,H)
//   xg = x @ W_ih^T + b_ih + b_hh                    (T,B,4H)
//   scan: g = xg_t + h @ W_hh^T ; gates i,f,g,o; c=f*c+i*tanh(g); h=o*tanh(c)
//   out[t,b] = dot(h_t[b], W_out) + b_out            (fused into the scan, O=1)
// Outputs flat fp32: out(32768) | hT(262144) | cT(262144)
//
// Memory-safe: time axis chunked by TC (chosen from ws_size); xg buffer is
// per-chunk. Output head fused via LDS partial + atomicAdd (no h history).
// ---------------------------------------------------------------------------

#define T_STEPS 128
#define BATCH   256
#define DIM     512
#define HID     1024
#define GATES   4096   // 4*HID

typedef __attribute__((ext_vector_type(8))) short short8;
typedef __attribute__((ext_vector_type(4))) float f4;

__device__ __forceinline__ short f2bf(float f) {
    union { float f; unsigned u; } x; x.f = f;
    unsigned r = (x.u + 0x7fffu + ((x.u >> 16) & 1u)) >> 16;
    return (short)r;
}
__device__ __forceinline__ float bf2f(short s) {
    union { unsigned u; float f; } x; x.u = ((unsigned)(unsigned short)s) << 16;
    return x.f;
}

__device__ __forceinline__ void gll16(const void* g, void* l) {
    __builtin_amdgcn_global_load_lds(
        (const __attribute__((address_space(1))) void*)g,
        (__attribute__((address_space(3))) void*)l, 16, 0, 0);
}

// ---------------- small helpers ----------------
__global__ __launch_bounds__(256) void cvt_f32_bf16(const float* __restrict__ in,
                                                    short* __restrict__ out, int n4) {
    int i = blockIdx.x * 256 + threadIdx.x;
    if (i < n4) {
        float4 v = ((const float4*)in)[i];
        union { short s[4]; long long ll; } r;
        r.s[0] = f2bf(v.x); r.s[1] = f2bf(v.y); r.s[2] = f2bf(v.z); r.s[3] = f2bf(v.w);
        ((long long*)out)[i] = r.ll;
    }
}

__global__ __launch_bounds__(256) void copy_f32v4(const float* __restrict__ in,
                                                  float* __restrict__ out, int n4) {
    int i = blockIdx.x * 256 + threadIdx.x;
    if (i < n4) ((float4*)out)[i] = ((const float4*)in)[i];
}

__global__ __launch_bounds__(256) void bias_sum(const float* __restrict__ a,
                                                const float* __restrict__ b,
                                                float* __restrict__ o, int n) {
    int i = blockIdx.x * 256 + threadIdx.x;
    if (i < n) o[i] = a[i] + b[i];
}

__global__ __launch_bounds__(256) void init_out(float* __restrict__ out,
                                                const float* __restrict__ b, int n) {
    int i = blockIdx.x * 256 + threadIdx.x;
    if (i < n) out[i] = b[0];
}

// ---------------- m97-style bf16 GEMM:  C(MxN) = A(MxK) @ B(NxK)^T + bias, opt relu
__global__ __launch_bounds__(256) void gemm_bt(const short* __restrict__ A,
                                               const short* __restrict__ B,
                                               const float* __restrict__ bias,
                                               short* __restrict__ C,
                                               int M, int N, int K, int do_relu) {
    __shared__ __align__(16) short As[128 * 32];
    __shared__ __align__(16) short Bs[128 * 32];
    const int tid = threadIdx.x, wave = tid >> 6, lane = tid & 63;
    const int wm = (wave >> 1) * 64, wn = (wave & 1) * 64;
    const int bm = blockIdx.x * 128, bn = blockIdx.y * 128;
    const int sr = lane >> 2, sc = (lane & 3) * 8;

    f4 acc[4][4] = {};

    for (int k0 = 0; k0 < K; k0 += 32) {
        __syncthreads();
#pragma unroll
        for (int j = 0; j < 2; ++j) {
            int c = wave * 2 + j;
            gll16(&A[(size_t)(bm + c * 16 + sr) * K + k0 + sc], &As[c * 512]);
            gll16(&B[(size_t)(bn + c * 16 + sr) * K + k0 + sc], &Bs[c * 512]);
        }
        __syncthreads();
        short8 af[4], bfr[4];
#pragma unroll
        for (int i = 0; i < 4; ++i) {
            af[i]  = *(const short8*)&As[(wm + i * 16 + (lane & 15)) * 32 + (lane >> 4) * 8];
            bfr[i] = *(const short8*)&Bs[(wn + i * 16 + (lane & 15)) * 32 + (lane >> 4) * 8];
        }
#pragma unroll
        for (int i = 0; i < 4; ++i)
#pragma unroll
            for (int j = 0; j < 4; ++j)
                acc[i][j] = __builtin_amdgcn_mfma_f32_16x16x32_bf16(af[i], bfr[j], acc[i][j], 0, 0, 0);
    }

    const int lc = lane & 15, lr = (lane >> 4) * 4;
#pragma unroll
    for (int i = 0; i < 4; ++i) {
#pragma unroll
        for (int j = 0; j < 4; ++j) {
            int col = bn + wn + j * 16 + lc;
            float bv = bias[col];
#pragma unroll
            for (int r = 0; r < 4; ++r) {
                int row = bm + wm + i * 16 + lr + r;
                float v = acc[i][j][r] + bv;
                if (do_relu) v = fmaxf(v, 0.f);
                C[(size_t)row * N + col] = f2bf(v);
            }
        }
    }
}

// ---------------- one LSTM timestep ----------------
// grid 256 blocks = 8 row-groups (32 batch) x 32 col-groups (32 h-cols).
// Wave g computes gate g's 32x32 preact tile (K=1024), then fused gate
// nonlinearity + c/h update + partial h.W_out reduction (atomicAdd into out).
__global__ __launch_bounds__(256) void lstm_step(const short* __restrict__ hprev,
                                                 const short* __restrict__ Whh,
                                                 const short* __restrict__ xg,
                                                 const float* __restrict__ Wout,
                                                 float* __restrict__ c,
                                                 short* __restrict__ hout,
                                                 float* __restrict__ outp,
                                                 float* __restrict__ hT,
                                                 float* __restrict__ cT) {
    __shared__ __align__(16) char smem[20480];
    short* As = (short*)smem;                  // 32x32 bf16 h tile      [0,2048)
    short* Bs = (short*)smem + 1024;           // 4x 32x32 bf16 W_hh     [2048,10240)
    float* gates = (float*)smem;               // reuse: 4x32x32 fp32    [0,16384)
    float* hw = (float*)(smem + 16384);        // 32x32 fp32 partials    [16384,20480)

    const int tid = threadIdx.x, wave = tid >> 6, lane = tid & 63;
    const int rg = blockIdx.x >> 5, cg = blockIdx.x & 31;
    const int rb = rg * 32, hc = cg * 32;
    const int sr = lane >> 2, sc = (lane & 3) * 8;

    f4 acc[2][2] = {};

    for (int k0 = 0; k0 < HID; k0 += 32) {
        __syncthreads();
        if (wave < 2)
            gll16(&hprev[(size_t)(rb + wave * 16 + sr) * HID + k0 + sc], &As[wave * 512]);
#pragma unroll
        for (int j = 0; j < 2; ++j)
            gll16(&Whh[(size_t)(wave * HID + hc + j * 16 + sr) * HID + k0 + sc],
                  &Bs[wave * 1024 + j * 512]);
        __syncthreads();
        short8 af[2], bfr[2];
#pragma unroll
        for (int i = 0; i < 2; ++i) {
            af[i]  = *(const short8*)&As[(i * 16 + (lane & 15)) * 32 + (lane >> 4) * 8];
            bfr[i] = *(const short8*)&Bs[wave * 1024 + (i * 16 + (lane & 15)) * 32 + (lane >> 4) * 8];
        }
#pragma unroll
        for (int i = 0; i < 2; ++i)
#pragma unroll
            for (int j = 0; j < 2; ++j)
                acc[i][j] = __builtin_amdgcn_mfma_f32_16x16x32_bf16(af[i], bfr[j], acc[i][j], 0, 0, 0);
    }

    __syncthreads();   // As/Bs dead; reuse smem as `gates`
    const int lc = lane & 15, lr = (lane >> 4) * 4;
#pragma unroll
    for (int i = 0; i < 2; ++i)
#pragma unroll
        for (int j = 0; j < 2; ++j) {
            int coll = j * 16 + lc;
#pragma unroll
            for (int r = 0; r < 4; ++r) {
                int rowl = i * 16 + lr + r;
                float g = acc[i][j][r]
                        + bf2f(xg[(size_t)(rb + rowl) * GATES + wave * HID + hc + coll]);
                float a = (wave == 2) ? tanhf(g) : 1.f / (1.f + expf(-g));
                gates[wave * 1024 + rowl * 32 + coll] = a;
            }
        }
    __syncthreads();

#pragma unroll
    for (int e = 0; e < 4; ++e) {
        int idx = tid + 256 * e;             // 0..1023 ; idx = rowl*32+coll
        int rowl = idx >> 5, coll = idx & 31;
        float iv = gates[idx], fv = gates[1024 + idx];
        float gv = gates[2048 + idx], ov = gates[3072 + idx];
        size_t gi = (size_t)(rb + rowl) * HID + hc + coll;
        float cn = fv * c[gi] + iv * gv;
        float h = ov * tanhf(cn);
        c[gi] = cn;
        hout[gi] = f2bf(h);
        hw[idx] = h * Wout[hc + coll];
        if (hT) { hT[gi] = h; cT[gi] = cn; }
    }
    __syncthreads();

    if (tid < 32) {                          // per-row partial of h . W_out
        float s = 0.f;
#pragma unroll 8
        for (int j = 0; j < 32; ++j) s += hw[tid * 32 + j];
        atomicAdd(&outp[rb + tid], s);
    }
}

// ---------------------------------------------------------------------------
extern "C" void kernel_launch(void* const* d_in, const int* in_sizes, int n_in,
                              void* d_out, int out_size, void* d_ws, size_t ws_size,
                              hipStream_t stream) {
    const float* inputs = (const float*)d_in[0];   // T,B,D
    const float* h0     = (const float*)d_in[1];   // 1,B,H
    const float* c0     = (const float*)d_in[2];   // 1,B,H
    const float* W1     = (const float*)d_in[3];   // H,D
    const float* b1     = (const float*)d_in[4];   // H
    const float* W_ih   = (const float*)d_in[5];   // 4H,H
    const float* W_hh   = (const float*)d_in[6];   // 4H,H
    const float* b_ih   = (const float*)d_in[7];   // 4H
    const float* b_hh   = (const float*)d_in[8];   // 4H
    const float* W_out  = (const float*)d_in[9];   // O,H
    const float* b_out  = (const float*)d_in[10];  // O

    float* out = (float*)d_out;                 // 32768
    float* hT  = out + (size_t)T_STEPS * BATCH; // 262144
    float* cT  = hT + (size_t)BATCH * HID;      // 262144

    // ---- workspace carve-up (256B-aligned) ----
    char* base = (char*)d_ws;
    size_t off = 0;
    auto alloc = [&](size_t bytes) -> char* {
        char* q = base + off;
        off += (bytes + 255) & ~(size_t)255;
        return q;
    };
    short* W1b   = (short*)alloc((size_t)HID * DIM * 2);        // 1 MB
    short* Wihb  = (short*)alloc((size_t)GATES * HID * 2);      // 8 MB
    short* Whhb  = (short*)alloc((size_t)GATES * HID * 2);      // 8 MB
    float* biasf = (float*)alloc((size_t)GATES * 4);            // 16 KB
    float* cf    = (float*)alloc((size_t)BATCH * HID * 4);      // 1 MB
    short* hb    = (short*)alloc((size_t)2 * BATCH * HID * 2);  // 1 MB ping-pong

    // choose time-chunk TC so the per-chunk buffers fit in ws_size
    size_t per_t = (size_t)BATCH * (DIM + HID + GATES) * 2;     // 2.88 MB / step
    int TC = 32;
    while (TC > 1 && off + (size_t)TC * per_t + 65536 > ws_size) TC >>= 1;

    short* inb_c = (short*)alloc((size_t)TC * BATCH * DIM * 2);
    short* xb_c  = (short*)alloc((size_t)TC * BATCH * HID * 2);
    short* xgb_c = (short*)alloc((size_t)TC * BATCH * GATES * 2);

    // ---- weight/bias prep ----
    cvt_f32_bf16<<<(HID * DIM / 4 + 255) / 256, 256, 0, stream>>>(W1, W1b, HID * DIM / 4);
    cvt_f32_bf16<<<(GATES * HID / 4 + 255) / 256, 256, 0, stream>>>(W_ih, Wihb, GATES * HID / 4);
    cvt_f32_bf16<<<(GATES * HID / 4 + 255) / 256, 256, 0, stream>>>(W_hh, Whhb, GATES * HID / 4);
    bias_sum<<<(GATES + 255) / 256, 256, 0, stream>>>(b_ih, b_hh, biasf, GATES);
    cvt_f32_bf16<<<(BATCH * HID / 4 + 255) / 256, 256, 0, stream>>>(h0, hb, BATCH * HID / 4);
    copy_f32v4<<<(BATCH * HID / 4 + 255) / 256, 256, 0, stream>>>(c0, cf, BATCH * HID / 4);
    init_out<<<(T_STEPS * BATCH + 255) / 256, 256, 0, stream>>>(out, b_out, T_STEPS * BATCH);

    // ---- chunked pipeline ----
    for (int t0 = 0; t0 < T_STEPS; t0 += TC) {
        int Mc = TC * BATCH;
        cvt_f32_bf16<<<(Mc * DIM / 4 + 255) / 256, 256, 0, stream>>>(
            inputs + (size_t)t0 * BATCH * DIM, inb_c, Mc * DIM / 4);
        // x = relu(in @ W1^T + b1)        M=Mc N=1024 K=512
        gemm_bt<<<dim3(Mc / 128, HID / 128), 256, 0, stream>>>(
            inb_c, W1b, b1, xb_c, Mc, HID, DIM, 1);
        // xg = x @ W_ih^T + (b_ih+b_hh)   M=Mc N=4096 K=1024
        gemm_bt<<<dim3(Mc / 128, GATES / 128), 256, 0, stream>>>(
            xb_c, Wihb, biasf, xgb_c, Mc, GATES, HID, 0);
        for (int tt = 0; tt < TC; ++tt) {
            int t = t0 + tt;
            int last = (t == T_STEPS - 1);
            lstm_step<<<256, 256, 0, stream>>>(
                hb + (size_t)(t & 1) * BATCH * HID, Whhb,
                xgb_c + (size_t)tt * BATCH * GATES, W_out, cf,
                hb + (size_t)((t + 1) & 1) * BATCH * HID,
                out + (size_t)t * BATCH,
                last ? hT : nullptr, last ? cT : nullptr);
        }
    }
}

// Round 3
// 2912.821 us; speedup vs baseline: 1.0564x; 1.0564x over previous
//
#include <hip/hip_runtime.h>
#include <hip/hip_bf16.h>
#include <math.h>

// ---------------------------------------------------------------------------
// LSTM_55327768708454:  T=128 B=256 D=512 H=1024 O=1
//   x  = relu(inputs @ W1^T + b1)
//   xg = x @ W_ih^T + b_ih + b_hh      (W_ih rows pre-permuted to hc*4+g)
//   scan: g = xg_t + h @ W_hh^T ; c=f*c+i*tanh(g); h=o*tanh(c)
//   out[t,b] = dot(h_t[b], W_out) + b_out
// Outputs flat fp32: out(32768) | hT(262144) | cT(262144)
//
// Round 3: recurrence restructured. Per-step kernel, 512 blocks
// (2 batch-groups x 256 col-groups). Each block holds its 16-row W_hh strip
// in LDS as pre-swizzled MFMA B-fragments (read once per step), stages h via
// double-buffered global_load_lds, fuses gates + c/h update.
// ---------------------------------------------------------------------------

#define T_STEPS 128
#define BATCH   256
#define DIM     512
#define HID     1024
#define GATES   4096

typedef __attribute__((ext_vector_type(8))) short short8;
typedef __attribute__((ext_vector_type(4))) float f4;

__device__ __forceinline__ short f2bf(float f) {
    union { float f; unsigned u; } x; x.f = f;
    unsigned r = (x.u + 0x7fffu + ((x.u >> 16) & 1u)) >> 16;
    return (short)r;
}
__device__ __forceinline__ float bf2f(short s) {
    union { unsigned u; float f; } x; x.u = ((unsigned)(unsigned short)s) << 16;
    return x.f;
}

__device__ __forceinline__ void gll16(const void* g, void* l) {
    __builtin_amdgcn_global_load_lds(
        (const __attribute__((address_space(1))) void*)g,
        (__attribute__((address_space(3))) void*)l, 16, 0, 0);
}

// ---------------- helpers ----------------
__global__ __launch_bounds__(256) void cvt_f32_bf16(const float* __restrict__ in,
                                                    short* __restrict__ out, int n4) {
    int i = blockIdx.x * 256 + threadIdx.x;
    if (i < n4) {
        float4 v = ((const float4*)in)[i];
        union { short s[4]; long long ll; } r;
        r.s[0] = f2bf(v.x); r.s[1] = f2bf(v.y); r.s[2] = f2bf(v.z); r.s[3] = f2bf(v.w);
        ((long long*)out)[i] = r.ll;
    }
}

// out row r' = hc*4+g  <-  in row g*1024+hc   (rows of 1024 fp32 -> bf16)
__global__ __launch_bounds__(256) void cvt_permute_rows(const float* __restrict__ in,
                                                        short* __restrict__ out) {
    int r = blockIdx.x;                        // 0..4095
    int hc = r >> 2, g = r & 3;
    const float* src = in + (size_t)(g * HID + hc) * HID;
    short* dst = out + (size_t)r * HID;
    int c = threadIdx.x * 4;
    float4 v = *(const float4*)&src[c];
    union { short s[4]; long long ll; } p;
    p.s[0] = f2bf(v.x); p.s[1] = f2bf(v.y); p.s[2] = f2bf(v.z); p.s[3] = f2bf(v.w);
    *(long long*)&dst[c] = p.ll;
}

__global__ __launch_bounds__(256) void bias_sum_perm(const float* __restrict__ a,
                                                     const float* __restrict__ b,
                                                     float* __restrict__ o) {
    int r = blockIdx.x * 256 + threadIdx.x;    // permuted index
    int hc = r >> 2, g = r & 3;
    int src = g * HID + hc;
    o[r] = a[src] + b[src];
}

__global__ __launch_bounds__(256) void copy_f32v4(const float* __restrict__ in,
                                                  float* __restrict__ out, int n4) {
    int i = blockIdx.x * 256 + threadIdx.x;
    if (i < n4) ((float4*)out)[i] = ((const float4*)in)[i];
}

// ---------------- m97-style bf16 GEMM:  C = A @ B^T + bias, opt relu ----------------
__global__ __launch_bounds__(256) void gemm_bt(const short* __restrict__ A,
                                               const short* __restrict__ B,
                                               const float* __restrict__ bias,
                                               short* __restrict__ C,
                                               int M, int N, int K, int do_relu) {
    __shared__ __align__(16) short As[128 * 32];
    __shared__ __align__(16) short Bs[128 * 32];
    const int tid = threadIdx.x, wave = tid >> 6, lane = tid & 63;
    const int wm = (wave >> 1) * 64, wn = (wave & 1) * 64;
    const int bm = blockIdx.x * 128, bn = blockIdx.y * 128;
    const int sr = lane >> 2, sc = (lane & 3) * 8;

    f4 acc[4][4] = {};

    for (int k0 = 0; k0 < K; k0 += 32) {
        __syncthreads();
#pragma unroll
        for (int j = 0; j < 2; ++j) {
            int c = wave * 2 + j;
            gll16(&A[(size_t)(bm + c * 16 + sr) * K + k0 + sc], &As[c * 512]);
            gll16(&B[(size_t)(bn + c * 16 + sr) * K + k0 + sc], &Bs[c * 512]);
        }
        __syncthreads();
        short8 af[4], bfr[4];
#pragma unroll
        for (int i = 0; i < 4; ++i) {
            af[i]  = *(const short8*)&As[(wm + i * 16 + (lane & 15)) * 32 + (lane >> 4) * 8];
            bfr[i] = *(const short8*)&Bs[(wn + i * 16 + (lane & 15)) * 32 + (lane >> 4) * 8];
        }
#pragma unroll
        for (int i = 0; i < 4; ++i)
#pragma unroll
            for (int j = 0; j < 4; ++j)
                acc[i][j] = __builtin_amdgcn_mfma_f32_16x16x32_bf16(af[i], bfr[j], acc[i][j], 0, 0, 0);
    }

    const int lc = lane & 15, lr = (lane >> 4) * 4;
#pragma unroll
    for (int i = 0; i < 4; ++i) {
#pragma unroll
        for (int j = 0; j < 4; ++j) {
            int col = bn + wn + j * 16 + lc;
            float bv = bias[col];
#pragma unroll
            for (int r = 0; r < 4; ++r) {
                int row = bm + wm + i * 16 + lr + r;
                float v = acc[i][j][r] + bv;
                if (do_relu) v = fmaxf(v, 0.f);
                C[(size_t)row * N + col] = f2bf(v);
            }
        }
    }
}

// ---------------- one LSTM timestep, W_hh-strip resident ----------------
// 512 blocks: cg = bx&255 owns h-cols hc0=cg*4 (16 permuted W_hh rows);
// bg = bx>>8 owns batch rows bg*128..+128.
__global__ __launch_bounds__(256) void lstm_step2(const short* __restrict__ Whh,
                                                  const short* __restrict__ hprev,
                                                  const short* __restrict__ xg,
                                                  float* __restrict__ cst,
                                                  short* __restrict__ hnext,
                                                  float* __restrict__ hT,
                                                  float* __restrict__ cT) {
    __shared__ __align__(16) short Bf[16384];   // 32 KB: frag-ordered W_hh strip
    __shared__ __align__(16) short Ast[8192];   // 16 KB: 2 x 8KB h staging (reused as preact)
    const int tid = threadIdx.x, w = tid >> 6, lane = tid & 63;
    const int cg = blockIdx.x & 255, bg = blockIdx.x >> 8;
    const int hc0 = cg * 4, bb = bg * 128;

    // ---- fill W_hh B-fragments (strip rows cg*16..+16, frag order [c][lane]) ----
    {
        const short* src = Whh + (size_t)(cg * 16 + (lane & 15)) * HID + (lane >> 4) * 8;
#pragma unroll
        for (int i = 0; i < 8; ++i) {
            int c = w * 8 + i;
            short8 v = *(const short8*)(src + c * 32);
            *(short8*)&Bf[c * 512 + lane * 8] = v;
        }
    }

    const int srow = lane >> 2, sc8 = (lane & 3) * 8;
    // stage chunk c of h (128 rows x 32 k) into buffer buf; wave stages tiles 2w,2w+1
#define STAGE(buf, c)                                                              \
    {                                                                              \
        _Pragma("unroll")                                                          \
        for (int i = 0; i < 2; ++i) {                                              \
            int m = w * 2 + i;                                                     \
            gll16(&hprev[(size_t)(bb + m * 16 + srow) * HID + (c) * 32 + sc8],     \
                  &Ast[(buf) * 4096 + m * 512]);                                   \
        }                                                                          \
    }

    STAGE(0, 0)
    f4 acc[2] = {};
    for (int c = 0; c < 32; ++c) {
        __syncthreads();
        if (c < 31) STAGE((c + 1) & 1, c + 1)
        short8 bfr = *(const short8*)&Bf[c * 512 + lane * 8];
#pragma unroll
        for (int mt = 0; mt < 2; ++mt) {
            short8 af = *(const short8*)&Ast[(c & 1) * 4096 + (w * 2 + mt) * 512
                                             + (lane & 15) * 32 + (lane >> 4) * 8];
            acc[mt] = __builtin_amdgcn_mfma_f32_16x16x32_bf16(af, bfr, acc[mt], 0, 0, 0);
        }
    }
    __syncthreads();

    // ---- dump preact to LDS: rows=128 batch, cols=16 (hc_l*4+g), pitch 17 fp32 ----
    float* pf = (float*)Ast;
    {
        const int col = lane & 15, q = lane >> 4;
#pragma unroll
        for (int mt = 0; mt < 2; ++mt)
#pragma unroll
            for (int r = 0; r < 4; ++r)
                pf[(w * 32 + mt * 16 + q * 4 + r) * 17 + col] = acc[mt][r];
    }
    __syncthreads();

    // ---- fused gate math: thread -> (b = bb + tid/2, hc_l = (tid&1)*2 + {0,1}) ----
    const int b_l = tid >> 1;
    const size_t b = bb + b_l;
    const int hcl0 = (tid & 1) * 2;
    short8 xv = *(const short8*)&xg[b * GATES + (size_t)(hc0 + hcl0) * 4];
    float2 cv = *(const float2*)&cst[b * HID + hc0 + hcl0];
    float hv[2], cn[2];
#pragma unroll
    for (int e = 0; e < 2; ++e) {
        int jb = (hcl0 + e) * 4;
        float gi = pf[b_l * 17 + jb + 0] + bf2f(xv[e * 4 + 0]);
        float gf = pf[b_l * 17 + jb + 1] + bf2f(xv[e * 4 + 1]);
        float gg = pf[b_l * 17 + jb + 2] + bf2f(xv[e * 4 + 2]);
        float go = pf[b_l * 17 + jb + 3] + bf2f(xv[e * 4 + 3]);
        float si = 1.f / (1.f + expf(-gi)), sf = 1.f / (1.f + expf(-gf));
        float tg = tanhf(gg),               so = 1.f / (1.f + expf(-go));
        float cc = e ? cv.y : cv.x;
        cn[e] = sf * cc + si * tg;
        hv[e] = so * tanhf(cn[e]);
    }
    *(float2*)&cst[b * HID + hc0 + hcl0] = make_float2(cn[0], cn[1]);
    unsigned hp = (unsigned)(unsigned short)f2bf(hv[0]) | ((unsigned)(unsigned short)f2bf(hv[1]) << 16);
    *(unsigned*)&hnext[b * HID + hc0 + hcl0] = hp;
    if (hT) {
        *(float2*)&hT[b * HID + hc0 + hcl0] = make_float2(hv[0], hv[1]);
        *(float2*)&cT[b * HID + hc0 + hcl0] = make_float2(cn[0], cn[1]);
    }
}

// ---------------- output head over one chunk of h history ----------------
__global__ __launch_bounds__(256) void out_head(const short* __restrict__ hs,
                                                const float* __restrict__ Wout,
                                                const float* __restrict__ bout,
                                                float* __restrict__ out) {
    int row = blockIdx.x * 4 + (threadIdx.x >> 6);   // tt*256+b within chunk
    int lane = threadIdx.x & 63;
    const int* h2 = (const int*)(hs + ((size_t)row + BATCH) * HID);  // slot tt+1
    const float2* w2 = (const float2*)Wout;
    float s = 0.f;
#pragma unroll
    for (int j = 0; j < 8; ++j) {
        int idx = lane + 64 * j;
        int pk = h2[idx];
        float2 wv = w2[idx];
        union { unsigned u; float f; } lo, hi;
        lo.u = ((unsigned)pk) << 16;
        hi.u = ((unsigned)pk) & 0xffff0000u;
        s += lo.f * wv.x + hi.f * wv.y;
    }
#pragma unroll
    for (int off = 32; off; off >>= 1) s += __shfl_down(s, off);
    if (lane == 0) out[row] = s + bout[0];
}

// ---------------------------------------------------------------------------
extern "C" void kernel_launch(void* const* d_in, const int* in_sizes, int n_in,
                              void* d_out, int out_size, void* d_ws, size_t ws_size,
                              hipStream_t stream) {
    const float* inputs = (const float*)d_in[0];
    const float* h0     = (const float*)d_in[1];
    const float* c0     = (const float*)d_in[2];
    const float* W1     = (const float*)d_in[3];
    const float* b1     = (const float*)d_in[4];
    const float* W_ih   = (const float*)d_in[5];
    const float* W_hh   = (const float*)d_in[6];
    const float* b_ih   = (const float*)d_in[7];
    const float* b_hh   = (const float*)d_in[8];
    const float* W_out  = (const float*)d_in[9];
    const float* b_out  = (const float*)d_in[10];

    float* out = (float*)d_out;
    float* hT  = out + (size_t)T_STEPS * BATCH;
    float* cT  = hT + (size_t)BATCH * HID;

    char* base = (char*)d_ws;
    size_t off = 0;
    auto alloc = [&](size_t bytes) -> char* {
        char* q = base + off;
        off += (bytes + 255) & ~(size_t)255;
        return q;
    };
    short* W1b   = (short*)alloc((size_t)HID * DIM * 2);        // 1 MB
    short* Wihb  = (short*)alloc((size_t)GATES * HID * 2);      // 8 MB (row-permuted)
    short* Whhb  = (short*)alloc((size_t)GATES * HID * 2);      // 8 MB (row-permuted)
    float* biasf = (float*)alloc((size_t)GATES * 4);            // 16 KB (permuted)
    float* cf    = (float*)alloc((size_t)BATCH * HID * 4);      // 1 MB

    // pick time-chunk TC to fit ws
    size_t per_t = (size_t)BATCH * (DIM + HID + GATES) * 2 + (size_t)BATCH * HID * 2;
    int TC = 32;
    while (TC > 1 && off + (size_t)TC * per_t + (size_t)BATCH * HID * 2 + 65536 > ws_size)
        TC >>= 1;

    short* hhist = (short*)alloc((size_t)(TC + 1) * BATCH * HID * 2);  // 16.9 MB @TC=32
    short* inb_c = (short*)alloc((size_t)TC * BATCH * DIM * 2);
    short* xb_c  = (short*)alloc((size_t)TC * BATCH * HID * 2);
    short* xgb_c = (short*)alloc((size_t)TC * BATCH * GATES * 2);

    // ---- weight prep ----
    cvt_f32_bf16<<<(HID * DIM / 4 + 255) / 256, 256, 0, stream>>>(W1, W1b, HID * DIM / 4);
    cvt_permute_rows<<<GATES, 256, 0, stream>>>(W_ih, Wihb);
    cvt_permute_rows<<<GATES, 256, 0, stream>>>(W_hh, Whhb);
    bias_sum_perm<<<GATES / 256, 256, 0, stream>>>(b_ih, b_hh, biasf);
    cvt_f32_bf16<<<(BATCH * HID / 4 + 255) / 256, 256, 0, stream>>>(h0, hhist, BATCH * HID / 4);
    copy_f32v4<<<(BATCH * HID / 4 + 255) / 256, 256, 0, stream>>>(c0, cf, BATCH * HID / 4);

    // ---- chunked pipeline ----
    for (int t0 = 0; t0 < T_STEPS; t0 += TC) {
        int Mc = TC * BATCH;
        cvt_f32_bf16<<<(Mc * DIM / 4 + 255) / 256, 256, 0, stream>>>(
            inputs + (size_t)t0 * BATCH * DIM, inb_c, Mc * DIM / 4);
        gemm_bt<<<dim3(Mc / 128, HID / 128), 256, 0, stream>>>(
            inb_c, W1b, b1, xb_c, Mc, HID, DIM, 1);
        gemm_bt<<<dim3(Mc / 128, GATES / 128), 256, 0, stream>>>(
            xb_c, Wihb, biasf, xgb_c, Mc, GATES, HID, 0);

        for (int tt = 0; tt < TC; ++tt) {
            int t = t0 + tt;
            int last = (t == T_STEPS - 1);
            lstm_step2<<<512, 256, 0, stream>>>(
                Whhb,
                hhist + (size_t)tt * BATCH * HID,
                xgb_c + (size_t)tt * BATCH * GATES,
                cf,
                hhist + (size_t)(tt + 1) * BATCH * HID,
                last ? hT : nullptr, last ? cT : nullptr);
        }
        out_head<<<TC * BATCH / 4, 256, 0, stream>>>(hhist, W_out, b_out,
                                                     out + (size_t)t0 * BATCH);
        // carry h: slot TC -> slot 0 (bf16, 512 KB)
        copy_f32v4<<<(BATCH * HID * 2 / 16 + 255) / 256, 256, 0, stream>>>(
            (const float*)(hhist + (size_t)TC * BATCH * HID), (float*)hhist,
            BATCH * HID * 2 / 16);
    }
}

// Round 4
// 2536.284 us; speedup vs baseline: 1.2133x; 1.1485x over previous
//
#include <hip/hip_runtime.h>
#include <hip/hip_bf16.h>
#include <math.h>

// ---------------------------------------------------------------------------
// LSTM_55327768708454:  T=128 B=256 D=512 H=1024 O=1
// Round 4: barrier-free recurrence K-loop. Per-step kernel, grid 512 =
// 4 batch-groups(64 rows) x 128 col-groups(8 h-cols = 32 permuted W_hh rows).
// W_hh strip lives in LDS as MFMA B-fragments (one fill + one barrier);
// A-fragments (h) load straight from global into VGPRs each chunk.
// ---------------------------------------------------------------------------

#define T_STEPS 128
#define BATCH   256
#define DIM     512
#define HID     1024
#define GATES   4096

typedef __attribute__((ext_vector_type(8))) short short8;
typedef __attribute__((ext_vector_type(4))) float f4;

__device__ __forceinline__ short f2bf(float f) {
    union { float f; unsigned u; } x; x.f = f;
    unsigned r = (x.u + 0x7fffu + ((x.u >> 16) & 1u)) >> 16;
    return (short)r;
}
__device__ __forceinline__ float bf2f(short s) {
    union { unsigned u; float f; } x; x.u = ((unsigned)(unsigned short)s) << 16;
    return x.f;
}

__device__ __forceinline__ void gll16(const void* g, void* l) {
    __builtin_amdgcn_global_load_lds(
        (const __attribute__((address_space(1))) void*)g,
        (__attribute__((address_space(3))) void*)l, 16, 0, 0);
}

// ---------------- helpers ----------------
__global__ __launch_bounds__(256) void cvt_f32_bf16(const float* __restrict__ in,
                                                    short* __restrict__ out, int n4) {
    int i = blockIdx.x * 256 + threadIdx.x;
    if (i < n4) {
        float4 v = ((const float4*)in)[i];
        union { short s[4]; long long ll; } r;
        r.s[0] = f2bf(v.x); r.s[1] = f2bf(v.y); r.s[2] = f2bf(v.z); r.s[3] = f2bf(v.w);
        ((long long*)out)[i] = r.ll;
    }
}

// out row r' = hc*4+g  <-  in row g*1024+hc
__global__ __launch_bounds__(256) void cvt_permute_rows(const float* __restrict__ in,
                                                        short* __restrict__ out) {
    int r = blockIdx.x;
    int hc = r >> 2, g = r & 3;
    const float* src = in + (size_t)(g * HID + hc) * HID;
    short* dst = out + (size_t)r * HID;
    int c = threadIdx.x * 4;
    float4 v = *(const float4*)&src[c];
    union { short s[4]; long long ll; } p;
    p.s[0] = f2bf(v.x); p.s[1] = f2bf(v.y); p.s[2] = f2bf(v.z); p.s[3] = f2bf(v.w);
    *(long long*)&dst[c] = p.ll;
}

__global__ __launch_bounds__(256) void bias_sum_perm(const float* __restrict__ a,
                                                     const float* __restrict__ b,
                                                     float* __restrict__ o) {
    int r = blockIdx.x * 256 + threadIdx.x;
    int hc = r >> 2, g = r & 3;
    int src = g * HID + hc;
    o[r] = a[src] + b[src];
}

__global__ __launch_bounds__(256) void copy_f32v4(const float* __restrict__ in,
                                                  float* __restrict__ out, int n4) {
    int i = blockIdx.x * 256 + threadIdx.x;
    if (i < n4) ((float4*)out)[i] = ((const float4*)in)[i];
}

// ---------------- m97-style bf16 GEMM:  C = A @ B^T + bias, opt relu ----------------
__global__ __launch_bounds__(256) void gemm_bt(const short* __restrict__ A,
                                               const short* __restrict__ B,
                                               const float* __restrict__ bias,
                                               short* __restrict__ C,
                                               int M, int N, int K, int do_relu) {
    __shared__ __align__(16) short As[128 * 32];
    __shared__ __align__(16) short Bs[128 * 32];
    const int tid = threadIdx.x, wave = tid >> 6, lane = tid & 63;
    const int wm = (wave >> 1) * 64, wn = (wave & 1) * 64;
    const int bm = blockIdx.x * 128, bn = blockIdx.y * 128;
    const int sr = lane >> 2, sc = (lane & 3) * 8;

    f4 acc[4][4] = {};

    for (int k0 = 0; k0 < K; k0 += 32) {
        __syncthreads();
#pragma unroll
        for (int j = 0; j < 2; ++j) {
            int c = wave * 2 + j;
            gll16(&A[(size_t)(bm + c * 16 + sr) * K + k0 + sc], &As[c * 512]);
            gll16(&B[(size_t)(bn + c * 16 + sr) * K + k0 + sc], &Bs[c * 512]);
        }
        __syncthreads();
        short8 af[4], bfr[4];
#pragma unroll
        for (int i = 0; i < 4; ++i) {
            af[i]  = *(const short8*)&As[(wm + i * 16 + (lane & 15)) * 32 + (lane >> 4) * 8];
            bfr[i] = *(const short8*)&Bs[(wn + i * 16 + (lane & 15)) * 32 + (lane >> 4) * 8];
        }
#pragma unroll
        for (int i = 0; i < 4; ++i)
#pragma unroll
            for (int j = 0; j < 4; ++j)
                acc[i][j] = __builtin_amdgcn_mfma_f32_16x16x32_bf16(af[i], bfr[j], acc[i][j], 0, 0, 0);
    }

    const int lc = lane & 15, lr = (lane >> 4) * 4;
#pragma unroll
    for (int i = 0; i < 4; ++i) {
#pragma unroll
        for (int j = 0; j < 4; ++j) {
            int col = bn + wn + j * 16 + lc;
            float bv = bias[col];
#pragma unroll
            for (int r = 0; r < 4; ++r) {
                int row = bm + wm + i * 16 + lr + r;
                float v = acc[i][j][r] + bv;
                if (do_relu) v = fmaxf(v, 0.f);
                C[(size_t)row * N + col] = f2bf(v);
            }
        }
    }
}

// ---------------- one LSTM timestep, barrier-free K-loop ----------------
// grid 512: cg = bx&127 owns 8 h-cols (permuted W_hh rows cg*32..+32);
// bg = bx>>7 owns batch rows bg*64..+64. Wave w computes rows bb+w*16..+16.
__global__ __launch_bounds__(256) void lstm_step3(const short* __restrict__ Whh,
                                                  const short* __restrict__ hprev,
                                                  const short* __restrict__ xg,
                                                  float* __restrict__ cst,
                                                  short* __restrict__ hnext,
                                                  float* __restrict__ hT,
                                                  float* __restrict__ cT) {
    __shared__ __align__(16) short Bf[32768];   // 64 KB: frag-ordered W_hh strip
    const int tid = threadIdx.x, w = tid >> 6, lane = tid & 63;
    const int cg = blockIdx.x & 127, bg = blockIdx.x >> 7;
    const int hc0 = cg * 8, bb = bg * 64;
    const int strip0 = cg * 32;                 // permuted W_hh row base

    // ---- fill strip fragments: slot p = c*2+nt ; wave w fills p = w*16..+16 ----
#pragma unroll
    for (int i = 0; i < 16; ++i) {
        int p = w * 16 + i;
        int c = p >> 1, nt = p & 1;
        gll16(&Whh[(size_t)(strip0 + nt * 16 + (lane & 15)) * HID + c * 32 + (lane >> 4) * 8],
              &Bf[p * 512]);
    }
    __syncthreads();

    // ---- K-loop: A from global (no LDS, no barriers), B from resident LDS ----
    const short* aptr = hprev + (size_t)(bb + w * 16 + (lane & 15)) * HID + (lane >> 4) * 8;
    f4 acc0 = {}, acc1 = {};
#pragma unroll 8
    for (int c = 0; c < 32; ++c) {
        short8 af = *(const short8*)(aptr + c * 32);
        short8 b0 = *(const short8*)&Bf[(c * 2 + 0) * 512 + lane * 8];
        short8 b1 = *(const short8*)&Bf[(c * 2 + 1) * 512 + lane * 8];
        acc0 = __builtin_amdgcn_mfma_f32_16x16x32_bf16(af, b0, acc0, 0, 0, 0);
        acc1 = __builtin_amdgcn_mfma_f32_16x16x32_bf16(af, b1, acc1, 0, 0, 0);
    }
    __syncthreads();            // all waves finished reading Bf

    // ---- dump preact to LDS (alias Bf): 64 rows x 32 cols fp32, pitch 33 ----
    float* pf = (float*)Bf;
    {
        int m0 = w * 16 + (lane >> 4) * 4, col = lane & 15;
#pragma unroll
        for (int r = 0; r < 4; ++r) {
            pf[(m0 + r) * 33 + col]      = acc0[r];
            pf[(m0 + r) * 33 + 16 + col] = acc1[r];
        }
    }
    __syncthreads();

    // ---- fused gate math: thread -> (b_l = tid/4, hcl0 = (tid&3)*2 + {0,1}) ----
    const int b_l = tid >> 2;
    const int hcl0 = (tid & 3) * 2;
    const size_t b = bb + b_l;
    short8 xv = *(const short8*)&xg[b * GATES + (size_t)strip0 + hcl0 * 4];
    float2 cv = *(const float2*)&cst[b * HID + hc0 + hcl0];
    float hv[2], cn[2];
#pragma unroll
    for (int e = 0; e < 2; ++e) {
        int jb = (hcl0 + e) * 4;
        float gi = pf[b_l * 33 + jb + 0] + bf2f(xv[e * 4 + 0]);
        float gf = pf[b_l * 33 + jb + 1] + bf2f(xv[e * 4 + 1]);
        float gg = pf[b_l * 33 + jb + 2] + bf2f(xv[e * 4 + 2]);
        float go = pf[b_l * 33 + jb + 3] + bf2f(xv[e * 4 + 3]);
        float si = 1.f / (1.f + expf(-gi)), sf = 1.f / (1.f + expf(-gf));
        float tg = tanhf(gg),               so = 1.f / (1.f + expf(-go));
        float cc = e ? cv.y : cv.x;
        cn[e] = sf * cc + si * tg;
        hv[e] = so * tanhf(cn[e]);
    }
    *(float2*)&cst[b * HID + hc0 + hcl0] = make_float2(cn[0], cn[1]);
    unsigned hp = (unsigned)(unsigned short)f2bf(hv[0]) | ((unsigned)(unsigned short)f2bf(hv[1]) << 16);
    *(unsigned*)&hnext[b * HID + hc0 + hcl0] = hp;
    if (hT) {
        *(float2*)&hT[b * HID + hc0 + hcl0] = make_float2(hv[0], hv[1]);
        *(float2*)&cT[b * HID + hc0 + hcl0] = make_float2(cn[0], cn[1]);
    }
}

// ---------------- output head over one chunk of h history ----------------
__global__ __launch_bounds__(256) void out_head(const short* __restrict__ hs,
                                                const float* __restrict__ Wout,
                                                const float* __restrict__ bout,
                                                float* __restrict__ out) {
    int row = blockIdx.x * 4 + (threadIdx.x >> 6);
    int lane = threadIdx.x & 63;
    const int* h2 = (const int*)(hs + ((size_t)row + BATCH) * HID);
    const float2* w2 = (const float2*)Wout;
    float s = 0.f;
#pragma unroll
    for (int j = 0; j < 8; ++j) {
        int idx = lane + 64 * j;
        int pk = h2[idx];
        float2 wv = w2[idx];
        union { unsigned u; float f; } lo, hi;
        lo.u = ((unsigned)pk) << 16;
        hi.u = ((unsigned)pk) & 0xffff0000u;
        s += lo.f * wv.x + hi.f * wv.y;
    }
#pragma unroll
    for (int off = 32; off; off >>= 1) s += __shfl_down(s, off);
    if (lane == 0) out[row] = s + bout[0];
}

// ---------------------------------------------------------------------------
extern "C" void kernel_launch(void* const* d_in, const int* in_sizes, int n_in,
                              void* d_out, int out_size, void* d_ws, size_t ws_size,
                              hipStream_t stream) {
    const float* inputs = (const float*)d_in[0];
    const float* h0     = (const float*)d_in[1];
    const float* c0     = (const float*)d_in[2];
    const float* W1     = (const float*)d_in[3];
    const float* b1     = (const float*)d_in[4];
    const float* W_ih   = (const float*)d_in[5];
    const float* W_hh   = (const float*)d_in[6];
    const float* b_ih   = (const float*)d_in[7];
    const float* b_hh   = (const float*)d_in[8];
    const float* W_out  = (const float*)d_in[9];
    const float* b_out  = (const float*)d_in[10];

    float* out = (float*)d_out;
    float* hT  = out + (size_t)T_STEPS * BATCH;
    float* cT  = hT + (size_t)BATCH * HID;

    char* base = (char*)d_ws;
    size_t off = 0;
    auto alloc = [&](size_t bytes) -> char* {
        char* q = base + off;
        off += (bytes + 255) & ~(size_t)255;
        return q;
    };
    short* W1b   = (short*)alloc((size_t)HID * DIM * 2);
    short* Wihb  = (short*)alloc((size_t)GATES * HID * 2);      // row-permuted
    short* Whhb  = (short*)alloc((size_t)GATES * HID * 2);      // row-permuted
    float* biasf = (float*)alloc((size_t)GATES * 4);            // permuted
    float* cf    = (float*)alloc((size_t)BATCH * HID * 4);

    size_t per_t = (size_t)BATCH * (DIM + HID + GATES) * 2 + (size_t)BATCH * HID * 2;
    int TC = 32;
    while (TC > 1 && off + (size_t)TC * per_t + (size_t)BATCH * HID * 2 + 65536 > ws_size)
        TC >>= 1;

    short* hhist = (short*)alloc((size_t)(TC + 1) * BATCH * HID * 2);
    short* inb_c = (short*)alloc((size_t)TC * BATCH * DIM * 2);
    short* xb_c  = (short*)alloc((size_t)TC * BATCH * HID * 2);
    short* xgb_c = (short*)alloc((size_t)TC * BATCH * GATES * 2);

    // ---- weight prep ----
    cvt_f32_bf16<<<(HID * DIM / 4 + 255) / 256, 256, 0, stream>>>(W1, W1b, HID * DIM / 4);
    cvt_permute_rows<<<GATES, 256, 0, stream>>>(W_ih, Wihb);
    cvt_permute_rows<<<GATES, 256, 0, stream>>>(W_hh, Whhb);
    bias_sum_perm<<<GATES / 256, 256, 0, stream>>>(b_ih, b_hh, biasf);
    cvt_f32_bf16<<<(BATCH * HID / 4 + 255) / 256, 256, 0, stream>>>(h0, hhist, BATCH * HID / 4);
    copy_f32v4<<<(BATCH * HID / 4 + 255) / 256, 256, 0, stream>>>(c0, cf, BATCH * HID / 4);

    // ---- chunked pipeline ----
    for (int t0 = 0; t0 < T_STEPS; t0 += TC) {
        int Mc = TC * BATCH;
        cvt_f32_bf16<<<(Mc * DIM / 4 + 255) / 256, 256, 0, stream>>>(
            inputs + (size_t)t0 * BATCH * DIM, inb_c, Mc * DIM / 4);
        gemm_bt<<<dim3(Mc / 128, HID / 128), 256, 0, stream>>>(
            inb_c, W1b, b1, xb_c, Mc, HID, DIM, 1);
        gemm_bt<<<dim3(Mc / 128, GATES / 128), 256, 0, stream>>>(
            xb_c, Wihb, biasf, xgb_c, Mc, GATES, HID, 0);

        for (int tt = 0; tt < TC; ++tt) {
            int t = t0 + tt;
            int last = (t == T_STEPS - 1);
            lstm_step3<<<512, 256, 0, stream>>>(
                Whhb,
                hhist + (size_t)tt * BATCH * HID,
                xgb_c + (size_t)tt * BATCH * GATES,
                cf,
                hhist + (size_t)(tt + 1) * BATCH * HID,
                last ? hT : nullptr, last ? cT : nullptr);
        }
        out_head<<<TC * BATCH / 4, 256, 0, stream>>>(hhist, W_out, b_out,
                                                     out + (size_t)t0 * BATCH);
        copy_f32v4<<<(BATCH * HID * 2 / 16 + 255) / 256, 256, 0, stream>>>(
            (const float*)(hhist + (size_t)TC * BATCH * HID), (float*)hhist,
            BATCH * HID * 2 / 16);
    }
}